// Round 2
// baseline (239.490 us; speedup 1.0000x reference)
//
#include <hip/hip_runtime.h>

#define WIDTH  1024
#define HALF   512
#define DEPTH  32
#define BATCH  32768
#define PAIRS4 (HALF / 4)        // 128 float4 pairs per row
#define NTHREADS 256
#define NBLOCKS  2048            // NTHREADS*NBLOCKS = 524288 threads = total/8
#define ROWS_PER_THREAD 8
#define ROW_STRIDE 4096          // BATCH / ROWS_PER_THREAD

typedef float f4 __attribute__((ext_vector_type(4)));

// Depth scan collapses analytically: for pair j, sum s=x0+x1 is invariant,
// difference d=x0-x1 scales by g_j = prod_i (1 - 2*params[j,i]).
// out0 = 0.5*s + d*(0.5*g), out1 = 0.5*s - d*(0.5*g).
//
// Key structural fact: with this thread->work mapping, jv = tid & 127 is
// INVARIANT across a thread's 8 rows, so each thread needs only 4 of the
// 512 gains. Compute them per-thread (params is 64 KB, L2-resident) --
// no LDS, no __syncthreads, no per-iteration ds_read.
__global__ void __launch_bounds__(NTHREADS)
butterfly_fused(const float* __restrict__ X,
                const float* __restrict__ params,
                float* __restrict__ out) {
    const int tid0  = blockIdx.x * NTHREADS + threadIdx.x;
    const int jv    = tid0 & (PAIRS4 - 1);      // float4-pair index, constant
    const int brow0 = tid0 >> 7;                // first row, 0..4095

    const float* xbase = X   + (long long)brow0 * WIDTH + 4 * jv;
    float*       obase = out + (long long)brow0 * WIDTH + 4 * jv;

    // Issue the first row's HBM loads BEFORE the gain math so the ~500-900
    // cycle miss latency hides under the product chain.
    f4 x0_0 = __builtin_nontemporal_load((const f4*)(xbase));
    f4 x1_0 = __builtin_nontemporal_load((const f4*)(xbase + HALF));

    // Per-thread gains for features j = 4*jv + r, r = 0..3.
    // Row j of params is 32 floats contiguous -> 8 aligned float4 loads.
    f4 g2;
#pragma unroll
    for (int r = 0; r < 4; ++r) {
        const f4* prow = (const f4*)(params + (4 * jv + r) * DEPTH);
        f4 prod = {1.0f, 1.0f, 1.0f, 1.0f};
#pragma unroll
        for (int c = 0; c < DEPTH / 4; ++c) {
            f4 p = prow[c];
            prod *= (1.0f - 2.0f * p);
        }
        g2[r] = 0.5f * (prod.x * prod.y * prod.z * prod.w);
    }

    // Row 0 (already loaded).
    {
        f4 h = 0.5f * (x0_0 + x1_0);
        f4 e = (x0_0 - x1_0) * g2;
        __builtin_nontemporal_store(h + e, (f4*)(obase));
        __builtin_nontemporal_store(h - e, (f4*)(obase + HALF));
    }

    // Rows 1..7: compile-time trip count -> full unroll, deep MLP.
#pragma unroll
    for (int k = 1; k < ROWS_PER_THREAD; ++k) {
        const long long off = (long long)k * ROW_STRIDE * WIDTH;
        f4 x0 = __builtin_nontemporal_load((const f4*)(xbase + off));
        f4 x1 = __builtin_nontemporal_load((const f4*)(xbase + off + HALF));
        f4 h = 0.5f * (x0 + x1);
        f4 e = (x0 - x1) * g2;
        __builtin_nontemporal_store(h + e, (f4*)(obase + off));
        __builtin_nontemporal_store(h - e, (f4*)(obase + off + HALF));
    }
}

extern "C" void kernel_launch(void* const* d_in, const int* in_sizes, int n_in,
                              void* d_out, int out_size, void* d_ws, size_t ws_size,
                              hipStream_t stream) {
    const float* X      = (const float*)d_in[0];
    const float* params = (const float*)d_in[1];
    float* out = (float*)d_out;

    hipLaunchKernelGGL(butterfly_fused, dim3(NBLOCKS), dim3(NTHREADS), 0, stream,
                       X, params, out);
}

// Round 4
// 227.418 us; speedup vs baseline: 1.0531x; 1.0531x over previous
//
#include <hip/hip_runtime.h>

#define WIDTH  1024
#define HALF   512
#define DEPTH  32
#define BATCH  32768
#define PAIRS4 (HALF / 4)        // 128 float4 pairs per row
#define NTHREADS 256
#define NBLOCKS  2048            // NTHREADS*NBLOCKS = 524288 threads = total/8
#define ROWS_PER_THREAD 8
#define ROW_STRIDE 4096          // BATCH / ROWS_PER_THREAD

typedef float f4 __attribute__((ext_vector_type(4)));

// Static device-side gain table (2 KB). Avoids any dependency on d_ws.
__device__ float g_gains[HALF];

// ---------------------------------------------------------------------------
// Kernel 1: compute per-feature half-gains g[j] = 0.5 * prod_i (1 - 2*p[j,i]).
// Only 512 threads total -> the uncoalesced 512B-lane-stride params reads cost
// ~4k transactions across 2 CUs (~0.5 us), vs ~16.7M when every main-kernel
// thread did this itself (the Round-2 bottleneck: ~1 GB of L2 traffic).
// ---------------------------------------------------------------------------
__global__ void __launch_bounds__(256)
compute_gains(const float* __restrict__ params) {
    const int j = blockIdx.x * 256 + threadIdx.x;   // 0..511
    const f4* prow = (const f4*)(params + j * DEPTH);
    f4 prod = {1.0f, 1.0f, 1.0f, 1.0f};
#pragma unroll
    for (int c = 0; c < DEPTH / 4; ++c) {
        f4 p = prow[c];
        prod *= (1.0f - 2.0f * p);
    }
    g_gains[j] = 0.5f * (prod.x * prod.y * prod.z * prod.w);
}

// ---------------------------------------------------------------------------
// Kernel 2: pure stream. Depth scan collapses analytically: s=x0+x1 invariant,
// d=x0-x1 scales by g. out0 = 0.5*s + d*(0.5*g), out1 = 0.5*s - d*(0.5*g).
// jv = tid & 127 is invariant across a thread's 8 rows -> one coalesced 16B
// gain load per thread (L2-hit), then 16 X loads + 16 stores.
// ---------------------------------------------------------------------------
__global__ void __launch_bounds__(NTHREADS)
butterfly_fused(const float* __restrict__ X,
                float* __restrict__ out) {
    const int tid0  = blockIdx.x * NTHREADS + threadIdx.x;
    const int jv    = tid0 & (PAIRS4 - 1);      // float4-pair index, constant
    const int brow0 = tid0 >> 7;                // first row, 0..4095

    const float* xbase = X   + (long long)brow0 * WIDTH + 4 * jv;
    float*       obase = out + (long long)brow0 * WIDTH + 4 * jv;

    // One coalesced, L2-resident 16B load: lanes read consecutive 16B chunks.
    const f4 g2 = ((const f4*)g_gains)[jv];

    // Explicit 2-deep software pipeline: next row's loads are in flight while
    // the current row computes/stores.
    f4 x0 = __builtin_nontemporal_load((const f4*)(xbase));
    f4 x1 = __builtin_nontemporal_load((const f4*)(xbase + HALF));

#pragma unroll
    for (int k = 0; k < ROWS_PER_THREAD; ++k) {
        f4 n0, n1;
        if (k + 1 < ROWS_PER_THREAD) {
            const long long noff = (long long)(k + 1) * ROW_STRIDE * WIDTH;
            n0 = __builtin_nontemporal_load((const f4*)(xbase + noff));
            n1 = __builtin_nontemporal_load((const f4*)(xbase + noff + HALF));
        }
        const long long off = (long long)k * ROW_STRIDE * WIDTH;
        f4 h = 0.5f * (x0 + x1);
        f4 e = (x0 - x1) * g2;
        __builtin_nontemporal_store(h + e, (f4*)(obase + off));
        __builtin_nontemporal_store(h - e, (f4*)(obase + off + HALF));
        x0 = n0;
        x1 = n1;
    }
}

extern "C" void kernel_launch(void* const* d_in, const int* in_sizes, int n_in,
                              void* d_out, int out_size, void* d_ws, size_t ws_size,
                              hipStream_t stream) {
    const float* X      = (const float*)d_in[0];
    const float* params = (const float*)d_in[1];
    float* out = (float*)d_out;

    hipLaunchKernelGGL(compute_gains, dim3(2), dim3(256), 0, stream, params);
    hipLaunchKernelGGL(butterfly_fused, dim3(NBLOCKS), dim3(NTHREADS), 0, stream,
                       X, out);
}